// Round 1
// baseline (604.518 us; speedup 1.0000x reference)
//
#include <hip/hip_runtime.h>

// Problem constants (match reference)
#define N_NODES 50000
#define N_EDGES 800000
#define F_IN 128
#define H1 100
#define H2 200
#define F_OUT 16

// ---------------- CSR build ----------------

__global__ void count_kernel(const int* __restrict__ col, int* __restrict__ cnt, int n_edges) {
    int e = blockIdx.x * blockDim.x + threadIdx.x;
    if (e < n_edges) atomicAdd(&cnt[col[e]], 1);
}

__global__ void dis_kernel(const int* __restrict__ cnt, float* __restrict__ dis, int n) {
    int i = blockIdx.x * blockDim.x + threadIdx.x;
    if (i < n) dis[i] = rsqrtf((float)cnt[i] + 1.0f);  // +1 = self loop
}

// Single-block exclusive scan over n entries (n=50000), wave-shuffle based.
__global__ void scan_kernel(const int* __restrict__ cnt, int* __restrict__ offs, int n) {
    __shared__ int wsum[16];
    int tid = threadIdx.x, lane = tid & 63, wid = tid >> 6;
    int carry = 0;
    for (int base = 0; base < n; base += 1024) {
        int i = base + tid;
        int v = (i < n) ? cnt[i] : 0;
        int s = v;
#pragma unroll
        for (int d = 1; d < 64; d <<= 1) {
            int t = __shfl_up(s, d);
            if (lane >= d) s += t;
        }
        if (lane == 63) wsum[wid] = s;
        __syncthreads();
        if (wid == 0) {
            int ws = (lane < 16) ? wsum[lane] : 0;
#pragma unroll
            for (int d = 1; d < 16; d <<= 1) {
                int t = __shfl_up(ws, d);
                if (lane >= d) ws += t;
            }
            if (lane < 16) wsum[lane] = ws;  // inclusive wave-sums
        }
        __syncthreads();
        int wbase = wid ? wsum[wid - 1] : 0;
        if (i < n) offs[i] = carry + wbase + s - v;  // exclusive
        carry += wsum[15];
        __syncthreads();  // protect wsum before next chunk overwrites
    }
    if (tid == 0) offs[n] = carry;
}

__global__ void fill_kernel(const int* __restrict__ row, const int* __restrict__ col,
                            const int* __restrict__ offs, int* __restrict__ cursor,
                            int* __restrict__ csr, int n_edges) {
    int e = blockIdx.x * blockDim.x + threadIdx.x;
    if (e < n_edges) {
        int c = col[e];
        int p = offs[c] + atomicAdd(&cursor[c], 1);
        csr[p] = row[e];
    }
}

// ---------------- GEMM with dis-scale epilogue: out[n][c] = dis[n] * sum_k in[n][k]*W[k][c] ----------------
// One block covers RPB rows x all NO cols. in[] accesses are wave-uniform -> scalar loads;
// W accesses coalesced across threads.

template <int K, int NO, int RPB>
__global__ void gemm_scale_kernel(const float* __restrict__ in, const float* __restrict__ W,
                                  const float* __restrict__ dis, float* __restrict__ out) {
    int c = threadIdx.x;
    if (c >= NO) return;
    int n0 = blockIdx.x * RPB;
    const float* inr0 = in + n0 * K;
    float acc[RPB];
#pragma unroll
    for (int r = 0; r < RPB; ++r) acc[r] = 0.f;
    const float* Wc = W + c;
#pragma unroll 4
    for (int k = 0; k < K; ++k) {
        float w = Wc[k * NO];
#pragma unroll
        for (int r = 0; r < RPB; ++r) acc[r] = fmaf(inr0[r * K + k], w, acc[r]);
    }
#pragma unroll
    for (int r = 0; r < RPB; ++r) {
        int n = n0 + r;
        out[n * NO + c] = acc[r] * dis[n];
    }
}

// ---------------- Aggregation: out[n][f] = act( dis[n]*(y[n][f] + sum_{src in in(n)} y[src][f]) + b[f] ) ----------------
// One wave per node; lanes cover features.

template <int F, bool RELU>
__global__ void agg_kernel(const float* __restrict__ y, const int* __restrict__ offs,
                           const int* __restrict__ csr, const float* __restrict__ dis,
                           const float* __restrict__ bias, float* __restrict__ out, int n_nodes) {
    constexpr int J = (F + 63) / 64;
    int wave = threadIdx.x >> 6;
    int lane = threadIdx.x & 63;
    int n = blockIdx.x * 4 + wave;
    if (n >= n_nodes) return;

    float acc[J];
#pragma unroll
    for (int j = 0; j < J; ++j) {
        int f = lane + j * 64;
        acc[j] = (f < F) ? y[n * F + f] : 0.f;  // self-loop term
    }
    int e0 = offs[n], e1 = offs[n + 1];
    for (int e = e0; e < e1; ++e) {
        int src = csr[e];
        const float* yr = y + src * F;
#pragma unroll
        for (int j = 0; j < J; ++j) {
            int f = lane + j * 64;
            if (f < F) acc[j] += yr[f];
        }
    }
    float d = dis[n];
#pragma unroll
    for (int j = 0; j < J; ++j) {
        int f = lane + j * 64;
        if (f < F) {
            float v = fmaf(acc[j], d, bias[f]);
            out[n * F + f] = RELU ? fmaxf(v, 0.f) : v;
        }
    }
}

// ---------------- Final FC: out[n][c] = h[n]@Wfc + bfc, thread handles (n, 4 cols) ----------------

__global__ void fc_kernel(const float* __restrict__ h, const float* __restrict__ W,
                          const float* __restrict__ b, float* __restrict__ out, int n_rows) {
    int idx = blockIdx.x * blockDim.x + threadIdx.x;
    int n = idx >> 2;
    int cg = (idx & 3) * 4;
    if (n >= n_rows) return;
    float a0 = 0.f, a1 = 0.f, a2 = 0.f, a3 = 0.f;
    const float* hr = h + n * H2;
#pragma unroll 2
    for (int k0 = 0; k0 < H2; k0 += 4) {
        float4 xv = *reinterpret_cast<const float4*>(hr + k0);
        float xs[4] = {xv.x, xv.y, xv.z, xv.w};
#pragma unroll
        for (int kk = 0; kk < 4; ++kk) {
            float4 wv = *reinterpret_cast<const float4*>(W + (k0 + kk) * F_OUT + cg);
            a0 = fmaf(xs[kk], wv.x, a0);
            a1 = fmaf(xs[kk], wv.y, a1);
            a2 = fmaf(xs[kk], wv.z, a2);
            a3 = fmaf(xs[kk], wv.w, a3);
        }
    }
    float4 bv = *reinterpret_cast<const float4*>(b + cg);
    float4 o = {a0 + bv.x, a1 + bv.y, a2 + bv.z, a3 + bv.w};
    *reinterpret_cast<float4*>(out + n * F_OUT + cg) = o;
}

// ---------------- Launch ----------------

extern "C" void kernel_launch(void* const* d_in, const int* in_sizes, int n_in,
                              void* d_out, int out_size, void* d_ws, size_t ws_size,
                              hipStream_t stream) {
    const float* x   = (const float*)d_in[0];
    const int*   ei  = (const int*)d_in[1];   // [2, E] int32 per harness convention
    const float* W1  = (const float*)d_in[2];
    const float* b1  = (const float*)d_in[3];
    const float* W2  = (const float*)d_in[4];
    const float* b2  = (const float*)d_in[5];
    const float* Wfc = (const float*)d_in[6];
    const float* bfc = (const float*)d_in[7];
    float* out = (float*)d_out;

    const int N = N_NODES, E = N_EDGES;
    const int* row = ei;
    const int* col = ei + E;

    // Workspace layout (~84 MB total)
    char* ws = (char*)d_ws;
    int*   cnt    = (int*)ws;    ws += (size_t)N * 4;
    int*   cursor = (int*)ws;    ws += (size_t)N * 4;
    float* dis    = (float*)ws;  ws += (size_t)N * 4;
    int*   offs   = (int*)ws;    ws += (size_t)(N + 1) * 4;
    int*   csr    = (int*)ws;    ws += (size_t)E * 4;
    float* y      = (float*)ws;  ws += (size_t)N * H2 * 4;
    float* h      = (float*)ws;  ws += (size_t)N * H2 * 4;

    hipMemsetAsync(cnt, 0, (size_t)N * 2 * 4, stream);  // cnt + cursor (contiguous)

    count_kernel<<<(E + 255) / 256, 256, 0, stream>>>(col, cnt, E);
    dis_kernel<<<(N + 255) / 256, 256, 0, stream>>>(cnt, dis, N);
    scan_kernel<<<1, 1024, 0, stream>>>(cnt, offs, N);
    fill_kernel<<<(E + 255) / 256, 256, 0, stream>>>(row, col, offs, cursor, csr, E);

    // Layer 1: y1 = (x@W1)*dis ; h1 = relu(dis*(agg y1) + b1)
    gemm_scale_kernel<F_IN, H1, 4><<<N / 4, 128, 0, stream>>>(x, W1, dis, y);
    agg_kernel<H1, true><<<N / 4, 256, 0, stream>>>(y, offs, csr, dis, b1, h, N);

    // Layer 2: y2 = (h1@W2)*dis ; h2 = relu(dis*(agg y2) + b2)
    gemm_scale_kernel<H1, H2, 4><<<N / 4, 256, 0, stream>>>(h, W2, dis, y);
    agg_kernel<H2, true><<<N / 4, 256, 0, stream>>>(y, offs, csr, dis, b2, h, N);

    // Final FC
    fc_kernel<<<(N * 4 + 255) / 256, 256, 0, stream>>>(h, Wfc, bfc, out, N);
}

// Round 3
// 446.846 us; speedup vs baseline: 1.3529x; 1.3529x over previous
//
#include <hip/hip_runtime.h>

// Problem constants (match reference)
#define N_NODES 50000
#define N_EDGES 800000
#define F_IN 128
#define H1 100
#define H2 200
#define F_OUT 16

// ---------------- CSR build ----------------

__global__ void count_kernel(const int* __restrict__ col, int* __restrict__ cnt, int n_edges) {
    int e = blockIdx.x * blockDim.x + threadIdx.x;
    if (e < n_edges) atomicAdd(&cnt[col[e]], 1);
}

__global__ void dis_kernel(const int* __restrict__ cnt, float* __restrict__ dis, int n) {
    int i = blockIdx.x * blockDim.x + threadIdx.x;
    if (i < n) dis[i] = rsqrtf((float)cnt[i] + 1.0f);  // +1 = self loop
}

// Single-block exclusive scan, int4-strided (n must be padded mult of 4 via guard).
__global__ void scan_kernel(const int* __restrict__ cnt, int* __restrict__ offs, int n4, int n) {
    __shared__ int wsum[16];
    int tid = threadIdx.x, lane = tid & 63, wid = tid >> 6;
    int carry = 0;
    const int4* c4 = (const int4*)cnt;
    int4* o4 = (int4*)offs;
    for (int base = 0; base < n4; base += 1024) {
        int i = base + tid;
        int4 v = (i < n4) ? c4[i] : make_int4(0, 0, 0, 0);
        int tsum = v.x + v.y + v.z + v.w;
        int s = tsum;
#pragma unroll
        for (int d = 1; d < 64; d <<= 1) {
            int t = __shfl_up(s, d);
            if (lane >= d) s += t;
        }
        if (lane == 63) wsum[wid] = s;
        __syncthreads();
        if (wid == 0) {
            int ws = (lane < 16) ? wsum[lane] : 0;
#pragma unroll
            for (int d = 1; d < 16; d <<= 1) {
                int t = __shfl_up(ws, d);
                if (lane >= d) ws += t;
            }
            if (lane < 16) wsum[lane] = ws;  // inclusive wave-sums
        }
        __syncthreads();
        int wbase = wid ? wsum[wid - 1] : 0;
        int total = wsum[15];
        int excl = carry + wbase + (s - tsum);
        if (i < n4) o4[i] = make_int4(excl, excl + v.x, excl + v.x + v.y, excl + v.x + v.y + v.z);
        carry += total;
        __syncthreads();  // protect wsum before next chunk overwrites
    }
    if (tid == 0) offs[n] = carry;
}

__global__ void fill_kernel(const int* __restrict__ row, const int* __restrict__ col,
                            const int* __restrict__ offs, int* __restrict__ cursor,
                            int* __restrict__ csr, int n_edges) {
    int e = blockIdx.x * blockDim.x + threadIdx.x;
    if (e < n_edges) {
        int c = col[e];
        int p = offs[c] + atomicAdd(&cursor[c], 1);
        csr[p] = row[e];
    }
}

// ---------------- GEMM with dis-scale epilogue: out[n][c] = dis[n] * sum_k in[n][k]*W[k][c] ----------------

template <int K, int NO, int RPB>
__global__ void gemm_scale_kernel(const float* __restrict__ in, const float* __restrict__ W,
                                  const float* __restrict__ dis, float* __restrict__ out) {
    int c = threadIdx.x;
    if (c >= NO) return;
    int n0 = blockIdx.x * RPB;
    const float* inr0 = in + n0 * K;
    float acc[RPB];
#pragma unroll
    for (int r = 0; r < RPB; ++r) acc[r] = 0.f;
    const float* Wc = W + c;
#pragma unroll 4
    for (int k = 0; k < K; ++k) {
        float w = Wc[k * NO];
#pragma unroll
        for (int r = 0; r < RPB; ++r) acc[r] = fmaf(inr0[r * K + k], w, acc[r]);
    }
#pragma unroll
    for (int r = 0; r < RPB; ++r) {
        int n = n0 + r;
        out[n * NO + c] = acc[r] * dis[n];
    }
}

// ---------------- Aggregation over 100-wide rows (float2, one wave per node) ----------------
// acc[n] = y[n] + sum_{src in in(n)} y[src]
// BIAS_RELU=true  : out[n] = relu(dis[n]*acc + b) * dis[n]   (layer-1 output, pre-scaled for layer-2 gather)
// BIAS_RELU=false : out[n] = dis[n]*acc                      (layer-2 aggregated input)

template <bool BIAS_RELU>
__global__ void agg100_kernel(const float* __restrict__ y, const int* __restrict__ offs,
                              const int* __restrict__ csr, const float* __restrict__ dis,
                              const float* __restrict__ bias, float* __restrict__ out, int n_nodes) {
    int wave = threadIdx.x >> 6, lane = threadIdx.x & 63;
    int n = blockIdx.x * 4 + wave;
    if (n >= n_nodes) return;
    const float2* Y = (const float2*)y;
    bool act = lane < 50;
    float ax = 0.f, ay = 0.f;
    if (act) {
        float2 v = Y[n * 50 + lane];  // self-loop term
        ax = v.x; ay = v.y;
    }
    int e0 = offs[n], e1 = offs[n + 1];
    for (int eb = e0; eb < e1; eb += 64) {
        int cdeg = min(e1 - eb, 64);
        int my = (lane < cdeg) ? csr[eb + lane] : 0;  // coalesced batch of edge srcs
        int i = 0;
        for (; i + 4 <= cdeg; i += 4) {
            int s0 = __shfl(my, i), s1 = __shfl(my, i + 1);
            int s2 = __shfl(my, i + 2), s3 = __shfl(my, i + 3);
            if (act) {
                float2 v0 = Y[s0 * 50 + lane];
                float2 v1 = Y[s1 * 50 + lane];
                float2 v2 = Y[s2 * 50 + lane];
                float2 v3 = Y[s3 * 50 + lane];
                ax += (v0.x + v1.x) + (v2.x + v3.x);
                ay += (v0.y + v1.y) + (v2.y + v3.y);
            }
        }
        for (; i < cdeg; ++i) {
            int s = __shfl(my, i);
            if (act) {
                float2 v = Y[s * 50 + lane];
                ax += v.x; ay += v.y;
            }
        }
    }
    if (act) {
        float d = dis[n];
        float ox, oy;
        if (BIAS_RELU) {
            int f = lane * 2;
            ox = fmaxf(fmaf(ax, d, bias[f]), 0.f) * d;
            oy = fmaxf(fmaf(ay, d, bias[f + 1]), 0.f) * d;
        } else {
            ox = ax * d;
            oy = ay * d;
        }
        ((float2*)out)[n * 50 + lane] = make_float2(ox, oy);
    }
}

// ---------------- Fused layer-2 GEMM + bias + relu + final FC ----------------
// h2[r][:] = relu(g2[n0+r] @ W2 + b2) (in LDS), then out[n0+r] = h2[r] @ Wfc + bfc.

__global__ void gemm2_fc_kernel(const float* __restrict__ g2, const float* __restrict__ W2,
                                const float* __restrict__ b2, const float* __restrict__ Wfc,
                                const float* __restrict__ bfc, float* __restrict__ out) {
    __shared__ float h2s[4][H2];
    int c = threadIdx.x;
    int n0 = blockIdx.x * 4;
    if (c < H2) {
        float acc[4] = {0.f, 0.f, 0.f, 0.f};
        const float* g0 = g2 + (size_t)n0 * H1;
        const float* Wc = W2 + c;
#pragma unroll 4
        for (int k = 0; k < H1; ++k) {
            float w = Wc[k * H2];
#pragma unroll
            for (int r = 0; r < 4; ++r) acc[r] = fmaf(g0[r * H1 + k], w, acc[r]);
        }
        float bb = b2[c];
#pragma unroll
        for (int r = 0; r < 4; ++r) h2s[r][c] = fmaxf(acc[r] + bb, 0.f);
    }
    __syncthreads();
    int wv = threadIdx.x >> 6, l = threadIdx.x & 63;
    if (l < F_OUT) {
        float a = bfc[l];
        const float* hr = h2s[wv];
#pragma unroll 8
        for (int k = 0; k < H2; ++k) a = fmaf(hr[k], Wfc[k * F_OUT + l], a);
        out[(n0 + wv) * F_OUT + l] = a;
    }
}

// ---------------- Launch ----------------

extern "C" void kernel_launch(void* const* d_in, const int* in_sizes, int n_in,
                              void* d_out, int out_size, void* d_ws, size_t ws_size,
                              hipStream_t stream) {
    const float* x   = (const float*)d_in[0];
    const int*   ei  = (const int*)d_in[1];
    const float* W1  = (const float*)d_in[2];
    const float* b1  = (const float*)d_in[3];
    const float* W2  = (const float*)d_in[4];
    const float* b2  = (const float*)d_in[5];
    const float* Wfc = (const float*)d_in[6];
    const float* bfc = (const float*)d_in[7];
    float* out = (float*)d_out;

    const int N = N_NODES, E = N_EDGES;
    const int* row = ei;
    const int* col = ei + E;

    // Workspace layout (16B-aligned sections)
    char* ws = (char*)d_ws;
    int*   cnt    = (int*)ws;    ws += (size_t)N * 4;        // 200,000 B
    int*   cursor = (int*)ws;    ws += (size_t)N * 4;        // 200,000 B
    float* dis    = (float*)ws;  ws += (size_t)N * 4;        // 200,000 B
    int*   offs   = (int*)ws;    ws += (size_t)(N + 4) * 4;  // 200,016 B (padded -> keeps 16B align)
    int*   csr    = (int*)ws;    ws += (size_t)E * 4;        // 3,200,000 B
    float* y1     = (float*)ws;  ws += (size_t)N * H1 * 4;   // 20 MB
    float* h1s    = (float*)ws;  ws += (size_t)N * H1 * 4;   // 20 MB
    float* g2     = (float*)ws;  ws += (size_t)N * H1 * 4;   // 20 MB

    hipMemsetAsync(cnt, 0, (size_t)N * 2 * 4, stream);  // cnt + cursor (contiguous)

    count_kernel<<<(E + 255) / 256, 256, 0, stream>>>(col, cnt, E);
    dis_kernel<<<(N + 255) / 256, 256, 0, stream>>>(cnt, dis, N);
    scan_kernel<<<1, 1024, 0, stream>>>(cnt, offs, N / 4, N);
    fill_kernel<<<(E + 255) / 256, 256, 0, stream>>>(row, col, offs, cursor, csr, E);

    // Layer 1 (GEMM first: thin side is H1=100 < F_IN=128):
    // y1 = (x@W1)*dis ; h1s = relu(dis*agg(y1) + b1) * dis
    gemm_scale_kernel<F_IN, H1, 4><<<N / 4, 128, 0, stream>>>(x, W1, dis, y1);
    agg100_kernel<true><<<N / 4, 256, 0, stream>>>(y1, offs, csr, dis, b1, h1s, N);

    // Layer 2 (aggregate first: thin side is H1=100 < H2=200):
    // g2 = dis*agg(h1s) ; out = relu(g2@W2 + b2) @ Wfc + bfc
    agg100_kernel<false><<<N / 4, 256, 0, stream>>>(h1s, offs, csr, dis, (const float*)nullptr, g2, N);
    gemm2_fc_kernel<<<N / 4, 256, 0, stream>>>(g2, W2, b2, Wfc, bfc, out);
}